// Round 13
// baseline (344.390 us; speedup 1.0000x reference)
//
#include <hip/hip_runtime.h>

// ResidualVQ: B=8, T=2048, D=256, Q=8, K=1024. N = B*T = 16384.
// Scoring via fp16 split-MFMA: 2x = xh + xl, e = eh + el (fp16 RTNE).
// 2x.e ~= xh.eh + xh.el + xl.eh  (dropped xl.el ~ 2e-6, below fp32 noise).
// score = acc - |e|^2  (row-constant |x|^2 dropped; same argmax).
//
// ROUND 13 = round 12 + (a) 32x32x16 MFMA (2382 vs 2075 TF ceiling, half the
// issue slots; C/D layout col=lane&31,row=(reg&3)+8*(reg>>2)+4*(lane>>5)),
// (b) chunk swizzle s=(row>>3)&3 (conflict-free for the 32x32 read pattern:
// rows r,r+8,r+16,r+24 now land in distinct bank-quads), (c) A-tile chunks
// 0,1 pre-staged BEFORE the update phase (latency hidden under update; the
// update's __syncthreads drains them), B staged after with counted vmcnt(4),
// (d) update loop unroll 2 for memory-latency overlap.
//
// d_out (float): [0, N*D) quantized_out; [N*D,+Q*N) indices; [+Q) losses
// d_ws: xb f16[2][N][512] | ecat f16[Q*K][512] | norms f32[Q*K]
//       | partial float2[2][4][N] (layer-parity double buffer)

typedef _Float16 f16;
typedef f16 f16x8 __attribute__((ext_vector_type(8)));
typedef float f32x4 __attribute__((ext_vector_type(4)));
typedef float f32x16 __attribute__((ext_vector_type(16)));

constexpr int Dd = 256;
constexpr int Kk = 1024;
constexpr int Qq = 8;
constexpr int Nn = 16384;

__device__ inline void gload16(const f16* g, f16* l) {
    __builtin_amdgcn_global_load_lds(
        (const __attribute__((address_space(1))) unsigned int*)(const __attribute__((address_space(1))) f16*)g,
        (__attribute__((address_space(3))) unsigned int*)(__attribute__((address_space(3))) f16*)l,
        16, 0, 0);
}

// ---- build ecat[Q*K][512] = [eh|el] + squared norms, from fp32 codebooks ----
__global__ __launch_bounds__(256) void build_ecat(const float* __restrict__ cb,
                                                  f16* __restrict__ ecat,
                                                  float* __restrict__ norms) {
    int row = blockIdx.x * 8 + (threadIdx.x >> 5);
    int p = threadIdx.x & 31;
    const float* s = cb + (size_t)row * Dd + p * 8;
    f16x8 hi, lo;
    float sq = 0.f;
#pragma unroll
    for (int j = 0; j < 8; ++j) {
        float v = s[j];
        f16 h = (f16)v;
        hi[j] = h; lo[j] = (f16)(v - (float)h);
        sq = fmaf(v, v, sq);
    }
    *(f16x8*)(ecat + (size_t)row * 512 + p * 8) = hi;
    *(f16x8*)(ecat + (size_t)row * 512 + 256 + p * 8) = lo;
#pragma unroll
    for (int off = 16; off >= 1; off >>= 1) sq += __shfl_down(sq, off, 32);
    if (p == 0) norms[row] = sq;
}

// ---- score layer q (+fused update of layer q-1) ----
// block = 256-code slice x 256 tokens, 8 waves (2 code-half x 4 token-quarter)
__global__ __launch_bounds__(512, 2) void score_kernel(
    const float* __restrict__ x,        // [N][256]
    const float* __restrict__ cb_prev,  // layer q-1 codebook [K][256] (q>0)
    const f16* __restrict__ ecat,       // this layer [K][512]
    const float* __restrict__ norms,    // this layer [K]
    const f16* __restrict__ xold,       // xb[(q-1)&1] (q>0 src; stable)
    f16* __restrict__ xnew,             // xb[q&1] (written; GEMM input)
    const float2* __restrict__ pin,     // partial layer q-1
    float2* __restrict__ pout,          // partial layer q
    float* __restrict__ idx_prev,       // [N] (q>0, slice0)
    float* __restrict__ loss_prev,      // scalar (q>0, slice0)
    int q)
{
    __shared__ f16 sEh[2][8192];      // 2 x 16 KB: 256 codes x 32 cols (eh)
    __shared__ f16 sEl[2][8192];      // 2 x 16 KB (el)
    __shared__ f16 sXh[2][8192];      // 2 x 16 KB: 256 tokens x 32 cols (xh)
    __shared__ f16 sXl[2][8192];      // 2 x 16 KB (xl)
    __shared__ float smn[256];
    __shared__ float2 smg[2][256];
    __shared__ float lred[8];

    const int tid = threadIdx.x;
    const int w = tid >> 6, l = tid & 63;
    const int wr = w >> 2, wc = w & 3;          // wr: code half, wc: token quarter
    const int l32 = l & 31, lh = l >> 5;

    // XCD-aligned: 4 slice-blocks of one 256-token tile share (b & 7).
    const int b = blockIdx.x;
    const int slice = (b >> 3) & 3;             // 256-code slice
    const int tokt = ((b >> 5) << 3) | (b & 7); // 64 token tiles
    const int tbase = tokt * 256;
    const int qcb = slice * 256;

    // Staging geometry: thread t -> LDS row t>>2, chunk t&3 (and row+128);
    // source col-chunk pre-swizzled with s(row) = (row>>3)&3 = (t>>5)&3.
    const int srow = tid >> 2;
    const int g = ((tid & 3) ^ ((tid >> 5) & 3)) * 8;
    const f16* gae = ecat + (size_t)(qcb + srow) * 512 + g;   // eh cols [0,256), el +256
    const f16* gbx = xnew + (size_t)(tbase + srow) * 512 + g; // xh cols [0,256), xl +256

#define STAGE_A(P, C) do { \
        int cc = (C) * 32; \
        gload16(gae + cc,             &sEh[P][tid * 8]); \
        gload16(gae + cc + 128 * 512, &sEh[P][4096 + tid * 8]); \
        gload16(gae + 256 + cc,             &sEl[P][tid * 8]); \
        gload16(gae + 256 + cc + 128 * 512, &sEl[P][4096 + tid * 8]); \
    } while (0)
#define STAGE_B(P, C) do { \
        int cc = (C) * 32; \
        gload16(gbx + cc,             &sXh[P][tid * 8]); \
        gload16(gbx + cc + 128 * 512, &sXh[P][4096 + tid * 8]); \
        gload16(gbx + 256 + cc,             &sXl[P][tid * 8]); \
        gload16(gbx + 256 + cc + 128 * 512, &sXl[P][4096 + tid * 8]); \
    } while (0)

    // Pre-stage A chunks 0,1 (ecat doesn't depend on the update phase);
    // their latency hides under the update; update's __syncthreads drains.
    STAGE_A(0, 0);
    STAGE_A(1, 1);

    // ================= fused update phase (layer q-1 -> xnew tile) ====
    {
        const int up = tid & 15;
        const int d0 = up * 16;
        float lp = 0.f;
#pragma unroll 2
        for (int pass = 0; pass < 8; ++pass) {
            const int row = tbase + pass * 32 + (tid >> 4);
            f16* xw = xnew + (size_t)row * 512;
            if (q == 0) {
                const float* xs = x + (size_t)row * Dd + d0;
#pragma unroll
                for (int c = 0; c < 2; ++c) {
                    f16x8 hi, lo;
#pragma unroll
                    for (int j = 0; j < 8; ++j) {
                        float v = 2.f * xs[c * 8 + j];
                        f16 h = (f16)v;
                        hi[j] = h; lo[j] = (f16)(v - (float)h);
                    }
                    *(f16x8*)(xw + d0 + c * 8) = hi;
                    *(f16x8*)(xw + 256 + d0 + c * 8) = lo;
                }
            } else {
                float2 bsel = pin[row];
#pragma unroll
                for (int s2 = 1; s2 < 4; ++s2) {
                    float2 c2 = pin[(size_t)s2 * Nn + row];
                    if (c2.x > bsel.x || (c2.x == bsel.x && c2.y < bsel.y)) bsel = c2;
                }
                const int k = (int)bsel.y;
                const float* e = cb_prev + (size_t)k * Dd + d0;
                const f16* xr = xold + (size_t)row * 512;
                f16x8 h0 = *(const f16x8*)(xr + d0);
                f16x8 h1 = *(const f16x8*)(xr + d0 + 8);
                f16x8 l0 = *(const f16x8*)(xr + 256 + d0);
                f16x8 l1 = *(const f16x8*)(xr + 256 + d0 + 8);
                float rn[16];
#pragma unroll
                for (int j = 0; j < 8; ++j) {
                    rn[j]     = ((float)h0[j] + (float)l0[j]) * 0.5f - e[j];
                    rn[8 + j] = ((float)h1[j] + (float)l1[j]) * 0.5f - e[8 + j];
                }
#pragma unroll
                for (int j = 0; j < 16; ++j) lp = fmaf(rn[j], rn[j], lp);
#pragma unroll
                for (int c = 0; c < 2; ++c) {
                    f16x8 hi, lo;
#pragma unroll
                    for (int j = 0; j < 8; ++j) {
                        float v = 2.f * rn[c * 8 + j];
                        f16 h = (f16)v;
                        hi[j] = h; lo[j] = (f16)(v - (float)h);
                    }
                    *(f16x8*)(xw + d0 + c * 8) = hi;
                    *(f16x8*)(xw + 256 + d0 + c * 8) = lo;
                }
                if (slice == 0 && up == 0) idx_prev[row] = (float)k;
            }
        }
        if (q > 0 && slice == 0) {
#pragma unroll
            for (int off = 32; off >= 1; off >>= 1) lp += __shfl_down(lp, off);
            if (l == 0) lred[w] = lp;
        }
    }
    if (tid < 256) smn[tid] = norms[qcb + tid];
    __syncthreads();   // drains vmcnt(0): xnew stores + pre-staged A landed
    if (q > 0 && slice == 0 && tid == 0) {
        float s = 0.f;
#pragma unroll
        for (int i = 0; i < 8; ++i) s += lred[i];
        atomicAdd(loss_prev, s * (1.0f / ((float)Nn * (float)Dd)));
    }

    // ================= GEMM phase (32x32x16, operand-sharing chunks) ========
    // ds_read offsets: frag (tile, k-half kh): row-in-256 per lane l32;
    // logical chunk lc = kh*2 + lh, stored at lc ^ ((row>>3)&3).
    int offA[4][2], offB[2][2];
#pragma unroll
    for (int m = 0; m < 4; ++m)
#pragma unroll
        for (int kh = 0; kh < 2; ++kh) {
            int row = wr * 128 + m * 32 + l32;
            offA[m][kh] = row * 32 + (((kh * 2 + lh) ^ ((row >> 3) & 3)) * 8);
        }
#pragma unroll
    for (int n = 0; n < 2; ++n)
#pragma unroll
        for (int kh = 0; kh < 2; ++kh) {
            int row = wc * 64 + n * 32 + l32;
            offB[n][kh] = row * 32 + (((kh * 2 + lh) ^ ((row >> 3) & 3)) * 8);
        }

    f32x16 acc[4][2];
#pragma unroll
    for (int m = 0; m < 4; ++m)
#pragma unroll
        for (int n = 0; n < 2; ++n) acc[m][n] = {};

    // prologue: B chunks 0,1 (xnew just written, L2-hot); wait chunk 0 only
    STAGE_B(0, 0);
    STAGE_B(1, 1);
    asm volatile("s_waitcnt vmcnt(4)\n\ts_barrier" ::: "memory");

#pragma unroll
    for (int c = 0; c < 8; ++c) {
        const int p = c & 1;
        if (c >= 1 && c < 7) { STAGE_A(p ^ 1, c + 1); STAGE_B(p ^ 1, c + 1); }
#pragma unroll
        for (int kh = 0; kh < 2; ++kh) {
            f16x8 aeh[4], bxh[2], bxl[2];
#pragma unroll
            for (int m = 0; m < 4; ++m) aeh[m] = *(const f16x8*)&sEh[p][offA[m][kh]];
#pragma unroll
            for (int n = 0; n < 2; ++n) bxh[n] = *(const f16x8*)&sXh[p][offB[n][kh]];
#pragma unroll
            for (int n = 0; n < 2; ++n) bxl[n] = *(const f16x8*)&sXl[p][offB[n][kh]];
            __builtin_amdgcn_s_setprio(1);
#pragma unroll
            for (int m = 0; m < 4; ++m)          // seg1: eh * xh
#pragma unroll
                for (int n = 0; n < 2; ++n)
                    acc[m][n] = __builtin_amdgcn_mfma_f32_32x32x16_f16(aeh[m], bxh[n], acc[m][n], 0, 0, 0);
#pragma unroll
            for (int m = 0; m < 4; ++m)          // seg3: eh * xl
#pragma unroll
                for (int n = 0; n < 2; ++n)
                    acc[m][n] = __builtin_amdgcn_mfma_f32_32x32x16_f16(aeh[m], bxl[n], acc[m][n], 0, 0, 0);
            __builtin_amdgcn_s_setprio(0);
            f16x8 ael[4];                        // reuses aeh's registers
#pragma unroll
            for (int m = 0; m < 4; ++m) ael[m] = *(const f16x8*)&sEl[p][offA[m][kh]];
            __builtin_amdgcn_s_setprio(1);
#pragma unroll
            for (int m = 0; m < 4; ++m)          // seg2: el * xh
#pragma unroll
                for (int n = 0; n < 2; ++n)
                    acc[m][n] = __builtin_amdgcn_mfma_f32_32x32x16_f16(ael[m], bxh[n], acc[m][n], 0, 0, 0);
            __builtin_amdgcn_s_setprio(0);
        }
        if (c < 7)
            asm volatile("s_waitcnt vmcnt(0)\n\ts_barrier" ::: "memory");
    }
#undef STAGE_A
#undef STAGE_B

    // epilogue: score = acc - |e|^2 ; top-1 (ascending code order).
    // C/D 32x32: token col = lane&31, code row = (reg&3)+8*(reg>>2)+4*(lane>>5).
    float bv[2]; int bi[2];
#pragma unroll
    for (int n = 0; n < 2; ++n) { bv[n] = -3.4e38f; bi[n] = 0; }
#pragma unroll
    for (int m = 0; m < 4; ++m) {
#pragma unroll
        for (int r = 0; r < 16; ++r) {
            int cl = wr * 128 + m * 32 + (r & 3) + 8 * (r >> 2) + 4 * lh;
            float nrm = smn[cl];
            int cg = qcb + cl;
#pragma unroll
            for (int n = 0; n < 2; ++n) {
                float v = acc[m][n][r] - nrm;
                if (v > bv[n]) { bv[n] = v; bi[n] = cg; }
            }
        }
    }
    // merge lanes l <-> l^32 (same token)
#pragma unroll
    for (int n = 0; n < 2; ++n) {
        float ov = __shfl_xor(bv[n], 32);
        int oi = __shfl_xor(bi[n], 32);
        if (ov > bv[n] || (ov == bv[n] && oi < bi[n])) { bv[n] = ov; bi[n] = oi; }
    }
    if (l < 32) {
#pragma unroll
        for (int n = 0; n < 2; ++n)
            smg[wr][wc * 64 + n * 32 + l] = make_float2(bv[n], (float)bi[n]);
    }
    __syncthreads();
    // merge the two code-half wave groups
    if (tid < 256) {
        float2 a = smg[0][tid], c = smg[1][tid];
        float2 r = (c.x > a.x || (c.x == a.x && c.y < a.y)) ? c : a;
        pout[(size_t)slice * Nn + tbase + tid] = r;
    }
}

// ---- final: merge partial(7), idx7, loss7, out = x - r8 ----
__global__ __launch_bounds__(256) void final_kernel(
    const float* __restrict__ x,
    const float* __restrict__ cb7,      // layer 7 codebook
    const f16* __restrict__ xcat,       // xb[1]: holds split(2*r7)
    const float2* __restrict__ pin,     // partial layer 7
    float* __restrict__ out,
    float* __restrict__ idx7,
    float* __restrict__ loss7)
{
    __shared__ float lsum[4];
    const int tid = threadIdx.x;
    const int row = blockIdx.x * 16 + (tid >> 4);
    const int d0 = (tid & 15) * 16;

    float2 bsel = pin[row];
#pragma unroll
    for (int s2 = 1; s2 < 4; ++s2) {
        float2 c2 = pin[(size_t)s2 * Nn + row];
        if (c2.x > bsel.x || (c2.x == bsel.x && c2.y < bsel.y)) bsel = c2;
    }
    const int k = (int)bsel.y;
    const float* e = cb7 + (size_t)k * Dd + d0;
    const f16* xr = xcat + (size_t)row * 512;
    const float* xs = x + (size_t)row * Dd + d0;
    float* os = out + (size_t)row * Dd + d0;

    f16x8 h0 = *(const f16x8*)(xr + d0);
    f16x8 h1 = *(const f16x8*)(xr + d0 + 8);
    f16x8 l0 = *(const f16x8*)(xr + 256 + d0);
    f16x8 l1 = *(const f16x8*)(xr + 256 + d0 + 8);
    float lp = 0.f;
#pragma unroll
    for (int j = 0; j < 8; ++j) {
        float r7a = ((float)h0[j] + (float)l0[j]) * 0.5f;
        float r7b = ((float)h1[j] + (float)l1[j]) * 0.5f;
        float r8a = r7a - e[j];
        float r8b = r7b - e[8 + j];
        os[j]     = xs[j] - r8a;
        os[8 + j] = xs[8 + j] - r8b;
        lp = fmaf(r8a, r8a, lp);
        lp = fmaf(r8b, r8b, lp);
    }
    if ((tid & 15) == 0) idx7[row] = (float)k;

#pragma unroll
    for (int off = 32; off >= 1; off >>= 1) lp += __shfl_down(lp, off);
    if ((tid & 63) == 0) lsum[tid >> 6] = lp;
    __syncthreads();
    if (tid == 0) {
        float s = lsum[0] + lsum[1] + lsum[2] + lsum[3];
        atomicAdd(loss7, s * (1.0f / ((float)Nn * (float)Dd)));
    }
}

extern "C" void kernel_launch(void* const* d_in, const int* in_sizes, int n_in,
                              void* d_out, int out_size, void* d_ws, size_t ws_size,
                              hipStream_t stream) {
    const float* x   = (const float*)d_in[0];   // [N,D]
    const float* cbs = (const float*)d_in[1];   // [Q,K,D]
    float* out    = (float*)d_out;
    float* idxs   = out + (size_t)Nn * Dd;        // [Q*N]
    float* losses = idxs + (size_t)Qq * Nn;       // [Q]

    f16* xb0     = (f16*)d_ws;                          // [N][512]
    f16* xb1     = xb0 + (size_t)Nn * 512;              // [N][512]
    f16* ecat    = xb1 + (size_t)Nn * 512;              // [Q*K][512]
    float* norms = (float*)(ecat + (size_t)Qq * Kk * 512);  // [Q*K]
    float2* part0 = (float2*)(norms + (size_t)Qq * Kk);     // [4][N]
    float2* part1 = part0 + (size_t)4 * Nn;                 // [4][N]

    hipMemsetAsync(losses, 0, Qq * sizeof(float), stream);
    build_ecat<<<(Qq * Kk) / 8, 256, 0, stream>>>(cbs, ecat, norms);

    for (int q = 0; q < Qq; ++q) {
        float2* pin  = (q & 1) ? part1 : part0;   // layer q-1 partials
        float2* pout = (q & 1) ? part0 : part1;   // layer q partials
        const f16* xold = (q & 1) ? xb0 : xb1;    // xb[(q-1)&1]
        f16* xnew       = (q & 1) ? xb1 : xb0;    // xb[q&1]
        score_kernel<<<256, 512, 0, stream>>>(
            x,
            q > 0 ? cbs + (size_t)(q - 1) * Kk * Dd : cbs,
            ecat + (size_t)q * Kk * 512, norms + (size_t)q * Kk,
            xold, xnew, pin, pout,
            q > 0 ? idxs + (size_t)(q - 1) * Nn : idxs,
            q > 0 ? losses + (q - 1) : losses,
            q);
    }
    // layer 7 partials: q=7 odd -> pout = part0; r7 split lives in xb[1]
    final_kernel<<<Nn / 16, 256, 0, stream>>>(
        x, cbs + (size_t)7 * Kk * Dd, xb1, part0, out,
        idxs + (size_t)7 * Nn, losses + 7);
}

// Round 14
// 289.205 us; speedup vs baseline: 1.1908x; 1.1908x over previous
//
#include <hip/hip_runtime.h>

// ResidualVQ: B=8, T=2048, D=256, Q=8, K=1024. N = B*T = 16384.
// Scoring via fp16 split-MFMA: 2x = xh + xl, e = eh + el (fp16 RTNE).
// 2x.e ~= xh.eh + xh.el + xl.eh  (dropped xl.el ~ 2e-6, below fp32 noise).
// score = acc - |e|^2  (row-constant |x|^2 dropped; same argmax).
//
// ROUND 14: FULLY-LOCAL single kernel. Block = 64 tokens x ALL 1024 codes
// -> argmax is block-local: no partials, no cross-block sync, no xcat,
// 8-layer loop + final output inside one launch (11 dispatches -> 3;
// ~15us/boundary measured from round 8->10 delta). Residual carried in
// REGISTERS (32 f32/thread, f32-exact). B tile (64 tok x [xh|xl]) built in
// LDS via swizzled ds_write_b128 (both-sides swizzle; B never gload_lds'd).
// A (eh|el) streamed: 4 passes x 256 codes x 8 col-chunks, r13's staging
// swizzle s(row)=(row>>3)&3, dbuf + vmcnt, 32x32x16 MFMA (r13-verified C/D
// mapping: col=lane&31, row=(reg&3)+8*(reg>>2)+4*(lane>>5)).
// LDS 134 KB, 1 block/CU, 8 waves (4 code-quads x 2 token-halves).
//
// d_out (float): [0, N*D) quantized_out; [N*D,+Q*N) indices; [+Q) losses
// d_ws: ecat f16[Q*K][512] | norms f32[Q*K]

typedef _Float16 f16;
typedef f16 f16x8 __attribute__((ext_vector_type(8)));
typedef float f32x16 __attribute__((ext_vector_type(16)));

constexpr int Dd = 256;
constexpr int Kk = 1024;
constexpr int Qq = 8;
constexpr int Nn = 16384;

__device__ inline void gload16(const f16* g, f16* l) {
    __builtin_amdgcn_global_load_lds(
        (const __attribute__((address_space(1))) unsigned int*)(const __attribute__((address_space(1))) f16*)g,
        (__attribute__((address_space(3))) unsigned int*)(__attribute__((address_space(3))) f16*)l,
        16, 0, 0);
}

// ---- build ecat[Q*K][512] = [eh|el] + squared norms, from fp32 codebooks ----
__global__ __launch_bounds__(256) void build_ecat(const float* __restrict__ cb,
                                                  f16* __restrict__ ecat,
                                                  float* __restrict__ norms) {
    int row = blockIdx.x * 8 + (threadIdx.x >> 5);
    int p = threadIdx.x & 31;
    const float* s = cb + (size_t)row * Dd + p * 8;
    f16x8 hi, lo;
    float sq = 0.f;
#pragma unroll
    for (int j = 0; j < 8; ++j) {
        float v = s[j];
        f16 h = (f16)v;
        hi[j] = h; lo[j] = (f16)(v - (float)h);
        sq = fmaf(v, v, sq);
    }
    *(f16x8*)(ecat + (size_t)row * 512 + p * 8) = hi;
    *(f16x8*)(ecat + (size_t)row * 512 + 256 + p * 8) = lo;
#pragma unroll
    for (int off = 16; off >= 1; off >>= 1) sq += __shfl_down(sq, off, 32);
    if (p == 0) norms[row] = sq;
}

// ---- the whole RVQ, one launch: block = 64 tokens through all 8 layers ----
__global__ __launch_bounds__(512, 2) void rvq_kernel(
    const float* __restrict__ x,      // [N][256]
    const float* __restrict__ cbs,    // [Q][K][256] fp32
    const f16* __restrict__ ecat,     // [Q*K][512]
    const float* __restrict__ norms,  // [Q*K]
    float* __restrict__ outq,         // d_out [N][256]
    float* __restrict__ idxs,         // d_out [Q][N] (as float)
    float* __restrict__ losses)       // d_out [Q]
{
    __shared__ f16 sA[2][16384];      // dbuf: [0,8192)=eh 256rx32c, [8192,16384)=el
    __shared__ f16 sB[32768];         // 16 sub-tiles [64r][32c]: 0-7 xh, 8-15 xl
    __shared__ float smn[1024];
    __shared__ float2 smg[4][64];
    __shared__ int bestk[64];
    __shared__ float lred[8];

    const int tid = threadIdx.x;
    const int w = tid >> 6, l = tid & 63;
    const int l32 = l & 31, lh = l >> 5;
    const int wcq = w >> 1;           // code quad 0..3 (64 codes each per cs)
    const int wt = w & 1;             // token half 0..1 (32 tokens each)
    const int tbase = blockIdx.x * 64;
    const int ut = tid >> 3, ud = tid & 7;   // token 0..63, dim-group 0..7
    const int grow = tbase + ut;

    // A staging geometry (r13 pattern): thread t -> rows tid>>2 (+128),
    // source col-chunk pre-swizzled with s(row)=(row>>3)&3 = (tid>>5)&3.
    const int srow = tid >> 2;
    const int g = ((tid & 3) ^ ((tid >> 5) & 3)) * 8;

    // ds_read offsets (global chunk qd=kh*2+lh read at slot qd^s(row))
    int offA_[2][2];
#pragma unroll
    for (int m = 0; m < 2; ++m)
#pragma unroll
        for (int kh = 0; kh < 2; ++kh) {
            int row = wcq * 64 + m * 32 + l32;
            offA_[m][kh] = row * 32 + (((kh * 2 + lh) ^ ((row >> 3) & 3)) * 8);
        }
    int rbh[2];
#pragma unroll
    for (int kh = 0; kh < 2; ++kh) {
        int row = wt * 32 + l32;
        rbh[kh] = row * 32 + (((kh * 2 + lh) ^ ((row >> 3) & 3)) * 8);
    }

    float r[32];   // residual: token ut, dims ud*32 .. ud*32+31

#define STAGE(P, pp, c) do { \
        const f16* ga_ = gqs + (size_t)(pp) * 131072 + (c) * 32; \
        gload16(ga_,                  &sA[P][tid * 8]); \
        gload16(ga_ + 128 * 512,      &sA[P][4096 + tid * 8]); \
        gload16(ga_ + 256,            &sA[P][8192 + tid * 8]); \
        gload16(ga_ + 256 + 128 * 512,&sA[P][12288 + tid * 8]); \
    } while (0)

#pragma unroll 1
    for (int q = 0; q < Qq; ++q) {
        const f16* gqs = ecat + ((size_t)q * Kk + srow) * 512 + g;
        // prestage A(p=0, c0,c1): latency hides under the update phase
        STAGE(0, 0, 0);
        STAGE(1, 0, 1);

        // ---- update phase (residual in registers) ----
        float lp = 0.f;
        if (q == 0) {
            const float4* xs = (const float4*)(x + (size_t)grow * Dd + ud * 32);
#pragma unroll
            for (int jv = 0; jv < 8; ++jv) {
                float4 v = xs[jv];
                r[jv * 4 + 0] = v.x; r[jv * 4 + 1] = v.y;
                r[jv * 4 + 2] = v.z; r[jv * 4 + 3] = v.w;
            }
        } else {
            const int k = bestk[ut];
            const float4* e4 = (const float4*)(cbs + ((size_t)(q - 1) * Kk + k) * Dd + ud * 32);
#pragma unroll
            for (int jv = 0; jv < 8; ++jv) {
                float4 v = e4[jv];
                r[jv * 4 + 0] -= v.x; r[jv * 4 + 1] -= v.y;
                r[jv * 4 + 2] -= v.z; r[jv * 4 + 3] -= v.w;
            }
#pragma unroll
            for (int j = 0; j < 32; ++j) lp = fmaf(r[j], r[j], lp);
            if ((tid & 7) == 0) idxs[(size_t)(q - 1) * Nn + grow] = (float)k;
#pragma unroll
            for (int off = 32; off >= 1; off >>= 1) lp += __shfl_down(lp, off);
            if (l == 0) lred[w] = lp;
        }
        // ---- build B tile in LDS: split(2r) -> xh sub-tile ud, xl 8+ud ----
        {
            const int s = (ut >> 3) & 3;
#pragma unroll
            for (int qd = 0; qd < 4; ++qd) {
                f16x8 hi, lo;
#pragma unroll
                for (int j = 0; j < 8; ++j) {
                    float v = 2.f * r[qd * 8 + j];
                    f16 h = (f16)v;
                    hi[j] = h; lo[j] = (f16)(v - (float)h);
                }
                int a = ud * 2048 + ut * 32 + ((qd ^ s) * 8);
                *(f16x8*)&sB[a] = hi;
                *(f16x8*)&sB[16384 + a] = lo;
            }
        }
        smn[tid] = norms[q * Kk + tid];
        smn[512 + tid] = norms[q * Kk + 512 + tid];
        __syncthreads();   // full drain: sB writes, prestaged A, global stores
        if (q > 0 && tid == 0) {
            float s2 = 0.f;
#pragma unroll
            for (int i = 0; i < 8; ++i) s2 += lred[i];
            atomicAdd(losses + q - 1, s2 * (1.0f / ((float)Nn * (float)Dd)));
        }

        // ---- GEMM: 4 cs passes x 256 codes x 8 chunks ----
        float bv = -3.4e38f; int bi = 0;
#pragma unroll 1
        for (int p = 0; p < 4; ++p) {
            f32x16 acc[2] = {};
#pragma unroll
            for (int c = 0; c < 8; ++c) {
                const int P = c & 1;
                if (c >= 1 && c < 7) STAGE(P ^ 1, p, c + 1);
#pragma unroll
                for (int kh = 0; kh < 2; ++kh) {
                    f16x8 a0 = *(const f16x8*)&sA[P][offA_[0][kh]];
                    f16x8 a1 = *(const f16x8*)&sA[P][offA_[1][kh]];
                    f16x8 bh = *(const f16x8*)&sB[c * 2048 + rbh[kh]];
                    f16x8 bl = *(const f16x8*)&sB[16384 + c * 2048 + rbh[kh]];
                    __builtin_amdgcn_s_setprio(1);
                    acc[0] = __builtin_amdgcn_mfma_f32_32x32x16_f16(a0, bh, acc[0], 0, 0, 0);
                    acc[1] = __builtin_amdgcn_mfma_f32_32x32x16_f16(a1, bh, acc[1], 0, 0, 0);
                    acc[0] = __builtin_amdgcn_mfma_f32_32x32x16_f16(a0, bl, acc[0], 0, 0, 0);
                    acc[1] = __builtin_amdgcn_mfma_f32_32x32x16_f16(a1, bl, acc[1], 0, 0, 0);
                    __builtin_amdgcn_s_setprio(0);
                    f16x8 e0 = *(const f16x8*)&sA[P][8192 + offA_[0][kh]];
                    f16x8 e1 = *(const f16x8*)&sA[P][8192 + offA_[1][kh]];
                    __builtin_amdgcn_s_setprio(1);
                    acc[0] = __builtin_amdgcn_mfma_f32_32x32x16_f16(e0, bh, acc[0], 0, 0, 0);
                    acc[1] = __builtin_amdgcn_mfma_f32_32x32x16_f16(e1, bh, acc[1], 0, 0, 0);
                    __builtin_amdgcn_s_setprio(0);
                }
                if (c < 7)
                    asm volatile("s_waitcnt vmcnt(0)\n\ts_barrier" ::: "memory");
            }
            asm volatile("s_barrier" ::: "memory");   // fence chunk-7 reads
            if (p < 3) { STAGE(0, p + 1, 0); STAGE(1, p + 1, 1); }
            // epilogue (overlaps next-cs staging latency); ascending code order
#pragma unroll
            for (int m = 0; m < 2; ++m) {
#pragma unroll
                for (int rr = 0; rr < 16; ++rr) {
                    int cl = wcq * 64 + m * 32 + (rr & 3) + 8 * (rr >> 2) + 4 * lh;
                    float v = acc[m][rr] - smn[p * 256 + cl];
                    int cg = p * 256 + cl;
                    if (v > bv) { bv = v; bi = cg; }
                }
            }
            if (p < 3)
                asm volatile("s_waitcnt vmcnt(4)\n\ts_barrier" ::: "memory");
        }
        // ---- merge: lanes l<->l^32 (same token), then the 4 code-quad waves ----
        {
            float ov = __shfl_xor(bv, 32);
            int oi = __shfl_xor(bi, 32);
            if (ov > bv || (ov == bv && oi < bi)) { bv = ov; bi = oi; }
            if (l < 32) smg[wcq][wt * 32 + l] = make_float2(bv, (float)bi);
            __syncthreads();
            if (tid < 64) {
                float2 r2 = smg[0][tid];
#pragma unroll
                for (int ww = 1; ww < 4; ++ww) {
                    float2 c2 = smg[ww][tid];
                    if (c2.x > r2.x || (c2.x == r2.x && c2.y < r2.y)) r2 = c2;
                }
                bestk[tid] = (int)r2.y;
            }
            __syncthreads();
        }
    }
#undef STAGE

    // ---- final: subtract e7, loss7, idx7, out = x - r8 ----
    {
        const int k = bestk[ut];
        const float4* e4 = (const float4*)(cbs + ((size_t)7 * Kk + k) * Dd + ud * 32);
        float lp = 0.f;
#pragma unroll
        for (int jv = 0; jv < 8; ++jv) {
            float4 v = e4[jv];
            r[jv * 4 + 0] -= v.x; r[jv * 4 + 1] -= v.y;
            r[jv * 4 + 2] -= v.z; r[jv * 4 + 3] -= v.w;
        }
#pragma unroll
        for (int j = 0; j < 32; ++j) lp = fmaf(r[j], r[j], lp);
        const float4* xs = (const float4*)(x + (size_t)grow * Dd + ud * 32);
        float4* os = (float4*)(outq + (size_t)grow * Dd + ud * 32);
#pragma unroll
        for (int jv = 0; jv < 8; ++jv) {
            float4 xv = xs[jv];
            float4 o;
            o.x = xv.x - r[jv * 4 + 0]; o.y = xv.y - r[jv * 4 + 1];
            o.z = xv.z - r[jv * 4 + 2]; o.w = xv.w - r[jv * 4 + 3];
            os[jv] = o;
        }
        if ((tid & 7) == 0) idxs[(size_t)7 * Nn + grow] = (float)k;
#pragma unroll
        for (int off = 32; off >= 1; off >>= 1) lp += __shfl_down(lp, off);
        if (l == 0) lred[w] = lp;
        __syncthreads();
        if (tid == 0) {
            float s2 = 0.f;
#pragma unroll
            for (int i = 0; i < 8; ++i) s2 += lred[i];
            atomicAdd(losses + 7, s2 * (1.0f / ((float)Nn * (float)Dd)));
        }
    }
}

extern "C" void kernel_launch(void* const* d_in, const int* in_sizes, int n_in,
                              void* d_out, int out_size, void* d_ws, size_t ws_size,
                              hipStream_t stream) {
    const float* x   = (const float*)d_in[0];   // [N,D]
    const float* cbs = (const float*)d_in[1];   // [Q,K,D]
    float* out    = (float*)d_out;
    float* idxs   = out + (size_t)Nn * Dd;        // [Q*N]
    float* losses = idxs + (size_t)Qq * Nn;       // [Q]

    f16* ecat    = (f16*)d_ws;                          // [Q*K][512]
    float* norms = (float*)(ecat + (size_t)Qq * Kk * 512);  // [Q*K]

    hipMemsetAsync(losses, 0, Qq * sizeof(float), stream);
    build_ecat<<<(Qq * Kk) / 8, 256, 0, stream>>>(cbs, ecat, norms);
    rvq_kernel<<<Nn / 64, 512, 0, stream>>>(x, cbs, ecat, norms,
                                            out, idxs, losses);
}